// Round 1
// baseline (721.865 us; speedup 1.0000x reference)
//
#include <hip/hip_runtime.h>
#include <math.h>

// ---------------------------------------------------------------------------
// UnitGCN (AGCN block) forward.  N=64, C=OC=64, T=300, V=25, S=3, IC=16.
// Decomposition:
//   K1: per (n, t-range): bf16 MFMA embed  E = [wa;wb](32x64) @ X(64x150)
//       (X flattened over (t,v) which is x's natural layout), then
//       scores += Ea^T Eb via MFMA over K=(t,k).  Partials -> ws.
//   K2: reduce partials, /4800, softmax over v, +A+PA -> att (fp32, ws).
//   K3: per (n, 3 t): P_s = Xt @ att_s (MFMA, V padded to 32, pads zeroed),
//       Z = [wd0|wd1|wd2](64x192) @ Pcat(192x25) (MFMA, 6 K-steps),
//       fused BN(+bd-sum)+residual+ReLU epilogue.
// MFMA convention (HW-verified m89/m91): D[m][n] = sum_k A_lane(m)[k]*B_lane(n)[k],
//   frag row = lane&15, k = (lane>>4)*8 + j ; C/D: col = lane&15, row = (lane>>4)*4+r.
// ---------------------------------------------------------------------------

typedef short  short4v  __attribute__((ext_vector_type(4)));
typedef short  short8v  __attribute__((ext_vector_type(8)));
typedef unsigned short ushort4v __attribute__((ext_vector_type(4)));
typedef float  float4v  __attribute__((ext_vector_type(4)));

#define MFMA_BF16(a,b,c) __builtin_amdgcn_mfma_f32_16x16x32_bf16((a),(b),(c),0,0,0)

__device__ __forceinline__ unsigned short f2bf(float f) {
  union { float f; unsigned int u; } v; v.f = f;
  unsigned int r = v.u + 0x7FFFu + ((v.u >> 16) & 1u);   // RNE
  return (unsigned short)(r >> 16);
}
__device__ __forceinline__ float bf2f(unsigned short h) {
  union { unsigned int u; float f; } v; v.u = ((unsigned int)h) << 16;
  return v.f;
}
// 8 bf16 from LDS via two ds_read_b64 (rows may be 8B- but not 16B-aligned)
__device__ __forceinline__ short8v ld8_b64(const unsigned short* p) {
  short4v a = *(const short4v*)p;
  short4v b = *(const short4v*)(p + 4);
  short8v r;
  r[0]=a[0]; r[1]=a[1]; r[2]=a[2]; r[3]=a[3];
  r[4]=b[0]; r[5]=b[1]; r[6]=b[2]; r[7]=b[3];
  return r;
}

// ============================ K1: attention scores ==========================
// grid (10, 64): blockIdx.x = t-split (30 t each), blockIdx.y = n. 128 threads.
// Wave w (0/1) splits embed by n-tile parity and scores by (s,tile) task id.
__global__ __launch_bounds__(128) void k1_scores(
    const float* __restrict__ x,  const float* __restrict__ wa,
    const float* __restrict__ ba, const float* __restrict__ wb,
    const float* __restrict__ bb, float* __restrict__ part)
{
  __shared__ __align__(16) unsigned short XT[160*68];    // [tv][c] bf16, stride 68
  __shared__ __align__(16) unsigned short ET[3][160*40]; // [s][tv][krow] bf16, stride 40
  __shared__ float biasL[96];
  const unsigned tid  = threadIdx.x;
  const unsigned lane = tid & 63u, w = tid >> 6;
  const unsigned l15  = lane & 15u, q = lane >> 4;
  const unsigned n = blockIdx.y, ts = blockIdx.x;
  const unsigned t0 = ts * 30u;

  for (unsigned i = tid; i < 96; i += 128) {
    unsigned s = i >> 5, r = i & 31u;
    biasL[i] = (r < 16) ? ba[s*16 + r] : bb[s*16 + (r-16)];
  }
  // zero XT pad rows 150..159 once (staging never touches them)
  for (unsigned i = tid; i < 10*68; i += 128) XT[150*68 + i] = 0;

  // preload W fragments: A[m=krow][k=c], krow<16 -> wa, else wb
  short8v Wf[3][2][2];
  #pragma unroll
  for (int s = 0; s < 3; ++s)
    #pragma unroll
    for (int mt = 0; mt < 2; ++mt)
      #pragma unroll
      for (int ks = 0; ks < 2; ++ks) {
        unsigned kr = mt*16 + l15;
        unsigned c0 = ks*32 + q*8;
        const float* src = (kr < 16) ? (wa + ((size_t)s*16 + kr)*64 + c0)
                                     : (wb + ((size_t)s*16 + (kr-16))*64 + c0);
        short8v f;
        #pragma unroll
        for (int j = 0; j < 8; ++j) f[j] = (short)f2bf(src[j]);
        Wf[s][mt][ks] = f;
      }

  float4v acc[6];
  #pragma unroll
  for (int j = 0; j < 6; ++j) acc[j] = (float4v){0.f,0.f,0.f,0.f};

  for (unsigned ch = 0; ch < 5; ++ch) {            // 5 chunks of 6 t
    const float* xb = x + (size_t)n*64*7500 + (size_t)(t0 + ch*6)*25;
    __syncthreads();                               // previous chunk readers done
    // stage XT[tv][c] (bf16, c-pairs packed into b32 writes; (t,v) is linear in x)
    for (unsigned i = tid; i < 4800; i += 128) {
      unsigned tv = i % 150u, cp = i / 150u;
      unsigned pk = (unsigned)f2bf(xb[(size_t)(2*cp)*7500 + tv])
                  | ((unsigned)f2bf(xb[(size_t)(2*cp+1)*7500 + tv]) << 16);
      *(unsigned*)(&XT[tv*68 + 2*cp]) = pk;
    }
    __syncthreads();
    // embed: E[krow][tv] = sum_c W[krow][c] * x[c][tv]  (+bias), store transposed
    for (unsigned nn = 0; nn < 5; ++nn) {
      unsigned nt  = w + 2*nn;                     // n-tile 0..9
      unsigned tvb = nt*16 + l15;
      short8v B0 = ld8_b64(&XT[tvb*68 + q*8]);         // c 0..31
      short8v B1 = ld8_b64(&XT[tvb*68 + 32 + q*8]);    // c 32..63
      #pragma unroll
      for (int s = 0; s < 3; ++s)
        #pragma unroll
        for (int mt = 0; mt < 2; ++mt) {
          float4v d = (float4v){0.f,0.f,0.f,0.f};
          d = MFMA_BF16(Wf[s][mt][0], B0, d);
          d = MFMA_BF16(Wf[s][mt][1], B1, d);
          unsigned krb = mt*16 + q*4;
          ushort4v pk;
          #pragma unroll
          for (int r = 0; r < 4; ++r) pk[r] = f2bf(d[r] + biasL[s*32 + krb + r]);
          *(ushort4v*)(&ET[s][tvb*40 + krb]) = pk;     // k-contiguous, 8B aligned
        }
    }
    __syncthreads();
    // scores: D[v][u] += sum_{t,k} Ea[k][t*25+v] * Eb[k][t*25+u]
    #pragma unroll
    for (int j = 0; j < 6; ++j) {
      unsigned g = (unsigned)j*2 + w;              // 12 (s,tile) tasks over 2 waves
      unsigned s = g >> 2, mt = (g >> 1) & 1u, nt2 = g & 1u;
      #pragma unroll
      for (int ks = 0; ks < 3; ++ks) {
        unsigned t    = 2*ks + (q >> 1);           // K* = t*16 + k
        unsigned kofs = 8*(q & 1u);
        short8v Af = *(const short8v*)(&ET[s][(t*25 + mt*16  + l15)*40 + kofs]);      // a rows
        short8v Bf = *(const short8v*)(&ET[s][(t*25 + nt2*16 + l15)*40 + 16 + kofs]); // b rows
        acc[j] = MFMA_BF16(Af, Bf, acc[j]);
      }
    }
  }
  // write partial scores
  #pragma unroll
  for (int j = 0; j < 6; ++j) {
    unsigned g = (unsigned)j*2 + w;
    unsigned s = g >> 2, mt = (g >> 1) & 1u, nt2 = g & 1u;
    unsigned u = nt2*16 + l15;
    if (u < 25) {
      #pragma unroll
      for (int r = 0; r < 4; ++r) {
        unsigned v = mt*16 + q*4 + (unsigned)r;
        if (v < 25)
          part[(((size_t)ts*64 + n)*3 + s)*625 + v*25 + u] = acc[j][r];
      }
    }
  }
}

// ====================== K2: reduce + softmax(v) + A + PA ====================
__global__ __launch_bounds__(128) void k2_softmax(
    const float* __restrict__ part, const float* __restrict__ A,
    const float* __restrict__ PA, float* __restrict__ att)
{
  unsigned tid = threadIdx.x, n = blockIdx.x;
  if (tid >= 75) return;
  unsigned s = tid / 25u, u = tid % 25u;
  float col[25];
  #pragma unroll
  for (int v = 0; v < 25; ++v) {
    float sum = 0.f;
    for (unsigned ts = 0; ts < 10; ++ts)
      sum += part[(((size_t)ts*64 + n)*3 + s)*625 + (unsigned)v*25 + u];
    col[v] = sum * (1.f/4800.f);
  }
  float m = col[0];
  #pragma unroll
  for (int v = 1; v < 25; ++v) m = fmaxf(m, col[v]);
  float S = 0.f;
  #pragma unroll
  for (int v = 0; v < 25; ++v) { col[v] = expf(col[v] - m); S += col[v]; }
  float inv = 1.f / S;
  #pragma unroll
  for (int v = 0; v < 25; ++v)
    att[(((size_t)n*3 + s)*25 + (unsigned)v)*25 + u] =
        col[v]*inv + A[s*625 + (unsigned)v*25 + u] + PA[s*625 + (unsigned)v*25 + u];
}

// ============== K3: y = x@att, z = Wd_cat@Pcat, BN+ReLU+residual ============
// grid (100, 64): 3 t per block, 256 threads = 4 waves; wave = m-tile (16 rows).
__global__ __launch_bounds__(256) void k3_main(
    const float* __restrict__ x,   const float* __restrict__ wd,
    const float* __restrict__ bd,  const float* __restrict__ gam,
    const float* __restrict__ bet, const float* __restrict__ mu,
    const float* __restrict__ var, const float* __restrict__ att,
    float* __restrict__ out)
{
  __shared__ __align__(16) unsigned short Xs[3*64*36];   // [t][c][v] bf16, stride 36, v>=25 zero
  __shared__ __align__(16) unsigned short WD[3*64*68];   // [s*64+o][c] bf16, stride 68
  __shared__ __align__(16) unsigned short AT[3*32*36];   // [s][u][v] = att[v][u], zero-padded
  __shared__ __align__(16) unsigned short Pt[32*196];    // [u][k=s*64+c] bf16
  __shared__ float KS[64], KB[64];
  const unsigned tid  = threadIdx.x;
  const unsigned lane = tid & 63u, w = tid >> 6;
  const unsigned l15  = lane & 15u, q = lane >> 4;
  const unsigned n = blockIdx.y, tb = blockIdx.x;
  const unsigned t0 = tb * 3u;

  if (tid < 64) {
    float sc = gam[tid] * rsqrtf(var[tid] + 1e-5f);
    KS[tid] = sc;
    KB[tid] = (bd[tid] + bd[64+tid] + bd[128+tid] - mu[tid]) * sc + bet[tid];
  }
  for (unsigned i = tid; i < 3*64*68; i += 256) {
    unsigned row = i / 68u, cc = i - row*68u;
    WD[i] = (cc < 64) ? f2bf(wd[(size_t)row*64 + cc]) : (unsigned short)0;
  }
  for (unsigned i = tid; i < 3*32*36; i += 256) {
    unsigned s = i / 1152u, r = i - s*1152u, u = r / 36u, v = r - u*36u;
    float a = (u < 25 && v < 25) ? att[(((size_t)n*3 + s)*25 + v)*25 + u] : 0.f;
    AT[i] = f2bf(a);
  }
  const float* xb = x + (size_t)n*64*7500 + (size_t)t0*25;
  for (unsigned i = tid; i < 3*64*36; i += 256) {
    unsigned c = i / 108u, r = i - c*108u, t = r / 36u, v = r - t*36u;
    float f = (v < 25) ? xb[(size_t)c*7500 + t*25 + v] : 0.f;
    Xs[(t*64 + c)*36 + v] = f2bf(f);
  }
  __syncthreads();

  const unsigned mt = w;   // wave owns 16 c-rows / o-rows
  for (unsigned t = 0; t < 3; ++t) {
    // ---- P phase: P[c][u] = sum_v x[c][v]*att[v][u]; store Pt[u][s*64+c] ----
    short8v Ax = ld8_b64(&Xs[(t*64 + mt*16 + l15)*36 + q*8]);
    #pragma unroll
    for (int s = 0; s < 3; ++s) {
      #pragma unroll
      for (int nt2 = 0; nt2 < 2; ++nt2) {
        short8v Bf = ld8_b64(&AT[((unsigned)s*32 + (unsigned)nt2*16 + l15)*36 + q*8]);
        float4v d = (float4v){0.f,0.f,0.f,0.f};
        d = MFMA_BF16(Ax, Bf, d);
        unsigned u  = (unsigned)nt2*16 + l15;
        unsigned kb = (unsigned)s*64 + mt*16 + q*4;
        ushort4v pk;
        #pragma unroll
        for (int r = 0; r < 4; ++r) pk[r] = f2bf(d[r]);
        *(ushort4v*)(&Pt[u*196 + kb]) = pk;
      }
    }
    __syncthreads();
    // ---- Z phase: Z[o][u] = sum_{s,c} wd[s][o][c] * P[s*64+c][u] ----
    float4v za = (float4v){0.f,0.f,0.f,0.f}, zb = (float4v){0.f,0.f,0.f,0.f};
    #pragma unroll
    for (int ks = 0; ks < 6; ++ks) {
      unsigned s  = (unsigned)ks >> 1;
      unsigned c0 = ((unsigned)ks & 1u)*32 + q*8;
      short8v Aw = ld8_b64(&WD[(s*64 + mt*16 + l15)*68 + c0]);
      short8v B0 = ld8_b64(&Pt[l15*196        + (unsigned)ks*32 + q*8]);
      short8v B1 = ld8_b64(&Pt[(16+l15)*196   + (unsigned)ks*32 + q*8]);
      za = MFMA_BF16(Aw, B0, za);
      zb = MFMA_BF16(Aw, B1, zb);
    }
    // ---- epilogue: BN + residual + ReLU ----
    #pragma unroll
    for (int nt2 = 0; nt2 < 2; ++nt2) {
      float4v zz = nt2 ? zb : za;
      unsigned u = (unsigned)nt2*16 + l15;
      if (u < 25) {
        #pragma unroll
        for (int r = 0; r < 4; ++r) {
          unsigned o = mt*16 + q*4 + (unsigned)r;
          float xv = xb[(size_t)o*7500 + t*25 + u];       // exact fp32 residual
          float val = zz[r]*KS[o] + KB[o] + xv;
          out[((size_t)n*64 + o)*7500 + (size_t)(t0 + t)*25 + u] = fmaxf(val, 0.f);
        }
      }
    }
    __syncthreads();   // Pt reads done before next t overwrites
  }
}

// ================================ launcher ==================================
extern "C" void kernel_launch(void* const* d_in, const int* in_sizes, int n_in,
                              void* d_out, int out_size, void* d_ws, size_t ws_size,
                              hipStream_t stream)
{
  (void)in_sizes; (void)n_in; (void)out_size; (void)ws_size;
  const float* x   = (const float*)d_in[0];
  const float* A   = (const float*)d_in[1];
  const float* PA  = (const float*)d_in[2];
  const float* wa  = (const float*)d_in[3];
  const float* ba  = (const float*)d_in[4];
  const float* wb  = (const float*)d_in[5];
  const float* bb  = (const float*)d_in[6];
  const float* wd  = (const float*)d_in[7];
  const float* bd  = (const float*)d_in[8];
  const float* gam = (const float*)d_in[9];
  const float* bet = (const float*)d_in[10];
  const float* mu  = (const float*)d_in[11];
  const float* var = (const float*)d_in[12];
  float* out  = (float*)d_out;
  float* part = (float*)d_ws;            // 10*64*3*625 = 1,200,000 f32 (4.8 MB)
  float* att  = part + 1200000;          // 64*3*625    =   120,000 f32

  hipLaunchKernelGGL(k1_scores, dim3(10, 64), dim3(128), 0, stream,
                     x, wa, ba, wb, bb, part);
  hipLaunchKernelGGL(k2_softmax, dim3(64), dim3(128), 0, stream,
                     part, A, PA, att);
  hipLaunchKernelGGL(k3_main, dim3(100, 64), dim3(256), 0, stream,
                     x, wd, bd, gam, bet, mu, var, att, out);
}

// Round 2
// 390.214 us; speedup vs baseline: 1.8499x; 1.8499x over previous
//
#include <hip/hip_runtime.h>
#include <math.h>

// ---------------------------------------------------------------------------
// UnitGCN (AGCN block) forward.  N=64, C=OC=64, T=300, V=25, S=3, IC=16.
//   K1: per (n, 30-t): embed E=[wa;wb](32x64)@X(64x150) with B-frags loaded
//       DIRECTLY from global (no LDS staging); ET round-trip in LDS; then
//       scores += Ea^T Eb via MFMA over K=(t,k). Partials -> ws.
//   K2: per (n,s): coalesced reduce of 10 partials, /4800, softmax over v,
//       +A+PA -> att (fp32, ws).
//   K3: per (n, 30-t): wd-frags + att^T-frags in REGISTERS (loaded once),
//       x A-frags direct from global; P_s = Xt@att_s (MFMA, v>=25 killed by
//       zero att rows); P->LDS transpose; Z = [wd]@Pcat (6 K-step MFMA);
//       fused BN(+bd-sum)+fp32-residual+ReLU epilogue.
// MFMA convention (HW-verified m89/m91): D[m][n] = sum_k A_lane(m)[k]*B_lane(n)[k],
//   frag row = lane&15, k = (lane>>4)*8 + j ; C/D: col = lane&15, row = (lane>>4)*4+r.
// ---------------------------------------------------------------------------

typedef short  short4v  __attribute__((ext_vector_type(4)));
typedef short  short8v  __attribute__((ext_vector_type(8)));
typedef unsigned short ushort4v __attribute__((ext_vector_type(4)));
typedef float  float4v  __attribute__((ext_vector_type(4)));

#define MFMA_BF16(a,b,c) __builtin_amdgcn_mfma_f32_16x16x32_bf16((a),(b),(c),0,0,0)

__device__ __forceinline__ unsigned short f2bf(float f) {
  union { float f; unsigned int u; } v; v.f = f;
  unsigned int r = v.u + 0x7FFFu + ((v.u >> 16) & 1u);   // RNE
  return (unsigned short)(r >> 16);
}
// 8 bf16 from LDS via two ds_read_b64 (rows 8B-aligned)
__device__ __forceinline__ short8v ld8_b64(const unsigned short* p) {
  short4v a = *(const short4v*)p;
  short4v b = *(const short4v*)(p + 4);
  short8v r;
  r[0]=a[0]; r[1]=a[1]; r[2]=a[2]; r[3]=a[3];
  r[4]=b[0]; r[5]=b[1]; r[6]=b[2]; r[7]=b[3];
  return r;
}

// ============================ K1: attention scores ==========================
// grid (10, 64): blockIdx.x = 30-t range, blockIdx.y = n. 128 threads, 2 waves.
__global__ __launch_bounds__(128) void k1_scores(
    const float* __restrict__ x,  const float* __restrict__ wa,
    const float* __restrict__ ba, const float* __restrict__ wb,
    const float* __restrict__ bb, float* __restrict__ part)
{
  __shared__ __align__(16) unsigned short ET[3][160*40]; // [s][tv][krow] bf16
  __shared__ float biasL[96];
  const unsigned tid  = threadIdx.x;
  const unsigned lane = tid & 63u, w = tid >> 6;
  const unsigned l15  = lane & 15u, q = lane >> 4;
  const unsigned n = blockIdx.y, ts = blockIdx.x;
  const unsigned t0 = ts * 30u;
  const float* xn = x + (size_t)n * 480000;

  for (unsigned i = tid; i < 96; i += 128) {
    unsigned s = i >> 5, r = i & 31u;
    biasL[i] = (r < 16) ? ba[s*16 + r] : bb[s*16 + (r-16)];
  }

  // W fragments in registers: A[m=krow][k=c], krow<16 -> wa, else wb
  short8v Wf[3][2][2];
  #pragma unroll
  for (int s = 0; s < 3; ++s)
    #pragma unroll
    for (int mt = 0; mt < 2; ++mt)
      #pragma unroll
      for (int ks = 0; ks < 2; ++ks) {
        unsigned kr = mt*16 + l15;
        unsigned c0 = ks*32 + q*8;
        const float* src = (kr < 16) ? (wa + ((size_t)s*16 + kr)*64 + c0)
                                     : (wb + ((size_t)s*16 + (kr-16))*64 + c0);
        short8v f;
        #pragma unroll
        for (int j = 0; j < 8; ++j) f[j] = (short)f2bf(src[j]);
        Wf[s][mt][ks] = f;
      }

  float4v acc[6];
  #pragma unroll
  for (int j = 0; j < 6; ++j) acc[j] = (float4v){0.f,0.f,0.f,0.f};

  __syncthreads();   // biasL ready

  for (unsigned ch = 0; ch < 5; ++ch) {            // 5 chunks of 6 t
    const unsigned tvbase = (t0 + ch*6u) * 25u;
    // ---- embed: B-frags direct from global; write E transposed to ET ----
    for (unsigned nn = 0; nn < 5; ++nn) {
      unsigned nt  = w + 2*nn;                     // tile 0..9
      unsigned tvb = nt*16 + l15;                  // local tv row
      unsigned tvg = tvbase + tvb;                 // global (t,v) flat index
      if (tvg > 7499u) tvg = 7499u;                // clamp (values discarded)
      short8v B0, B1;
      #pragma unroll
      for (int j = 0; j < 8; ++j) {
        B0[j] = (short)f2bf(xn[(size_t)(q*8 + (unsigned)j)*7500 + tvg]);
        B1[j] = (short)f2bf(xn[(size_t)(32 + q*8 + (unsigned)j)*7500 + tvg]);
      }
      #pragma unroll
      for (int s = 0; s < 3; ++s)
        #pragma unroll
        for (int mt = 0; mt < 2; ++mt) {
          float4v d = (float4v){0.f,0.f,0.f,0.f};
          d = MFMA_BF16(Wf[s][mt][0], B0, d);
          d = MFMA_BF16(Wf[s][mt][1], B1, d);
          unsigned krb = mt*16 + q*4;
          ushort4v pk;
          #pragma unroll
          for (int r = 0; r < 4; ++r) pk[r] = f2bf(d[r] + biasL[s*32 + krb + r]);
          *(ushort4v*)(&ET[s][tvb*40 + krb]) = pk;
        }
    }
    __syncthreads();
    // ---- scores: D[v][u] += sum_{t,k} Ea[k][t*25+v]*Eb[k][t*25+u] ----
    #pragma unroll
    for (int j = 0; j < 6; ++j) {
      unsigned g = (unsigned)j*2 + w;              // 12 (s,mt,nt2) tasks / 2 waves
      unsigned s = g >> 2, mt = (g >> 1) & 1u, nt2 = g & 1u;
      #pragma unroll
      for (int ks = 0; ks < 3; ++ks) {
        unsigned t    = 2*ks + (q >> 1);
        unsigned kofs = 8*(q & 1u);
        short8v Af = *(const short8v*)(&ET[s][(t*25 + mt*16  + l15)*40 + kofs]);
        short8v Bf = *(const short8v*)(&ET[s][(t*25 + nt2*16 + l15)*40 + 16 + kofs]);
        acc[j] = MFMA_BF16(Af, Bf, acc[j]);
      }
    }
    __syncthreads();
  }
  #pragma unroll
  for (int j = 0; j < 6; ++j) {
    unsigned g = (unsigned)j*2 + w;
    unsigned s = g >> 2, mt = (g >> 1) & 1u, nt2 = g & 1u;
    unsigned u = nt2*16 + l15;
    if (u < 25) {
      #pragma unroll
      for (int r = 0; r < 4; ++r) {
        unsigned v = mt*16 + q*4 + (unsigned)r;
        if (v < 25)
          part[(((size_t)ts*64 + n)*3 + s)*625 + v*25 + u] = acc[j][r];
      }
    }
  }
}

// ====================== K2: reduce + softmax(v) + A + PA ====================
// grid (3, 64): one block per (s, n). 256 threads.
__global__ __launch_bounds__(256) void k2_softmax(
    const float* __restrict__ part, const float* __restrict__ A,
    const float* __restrict__ PA, float* __restrict__ att)
{
  __shared__ float Sc[625];
  const unsigned tid = threadIdx.x, s = blockIdx.x, n = blockIdx.y;
  for (unsigned i = tid; i < 625; i += 256) {
    float sum = 0.f;
    #pragma unroll
    for (unsigned ts = 0; ts < 10; ++ts)
      sum += part[(((size_t)ts*64 + n)*3 + s)*625 + i];
    Sc[i] = sum * (1.f/4800.f);
  }
  __syncthreads();
  if (tid < 25) {
    unsigned u = tid;
    float col[25];
    float m = -1e30f;
    #pragma unroll
    for (int v = 0; v < 25; ++v) { col[v] = Sc[(unsigned)v*25 + u]; m = fmaxf(m, col[v]); }
    float S = 0.f;
    #pragma unroll
    for (int v = 0; v < 25; ++v) { col[v] = expf(col[v] - m); S += col[v]; }
    float inv = 1.f / S;
    #pragma unroll
    for (int v = 0; v < 25; ++v)
      att[(((size_t)n*3 + s)*25 + (unsigned)v)*25 + u] =
          col[v]*inv + A[s*625 + (unsigned)v*25 + u] + PA[s*625 + (unsigned)v*25 + u];
  }
}

// ============== K3: y = x@att, z = Wd_cat@Pcat, BN+ReLU+residual ============
// grid (10, 64): 30 t per block, 256 threads = 4 waves; wave = m-tile.
__global__ __launch_bounds__(256) void k3_main(
    const float* __restrict__ x,   const float* __restrict__ wd,
    const float* __restrict__ bd,  const float* __restrict__ gam,
    const float* __restrict__ bet, const float* __restrict__ mu,
    const float* __restrict__ var, const float* __restrict__ att,
    float* __restrict__ out)
{
  __shared__ __align__(16) unsigned short Pt[32*196];    // [u][k=s*64+c] bf16
  __shared__ float KS[64], KB[64];
  const unsigned tid  = threadIdx.x;
  const unsigned lane = tid & 63u, mt = tid >> 6;        // wave = c/o tile
  const unsigned l15  = lane & 15u, q = lane >> 4;
  const unsigned n = blockIdx.y, t0 = blockIdx.x * 30u;

  if (tid < 64) {
    float sc = gam[tid] * rsqrtf(var[tid] + 1e-5f);
    KS[tid] = sc;
    KB[tid] = (bd[tid] + bd[64+tid] + bd[128+tid] - mu[tid]) * sc + bet[tid];
  }
  // att^T B-frags in registers: B[n=u][k=v]; zeros for v>=25 (kills x garbage)
  short8v ATf[3][2];
  #pragma unroll
  for (int s = 0; s < 3; ++s)
    #pragma unroll
    for (int nt2 = 0; nt2 < 2; ++nt2) {
      unsigned u = (unsigned)nt2*16 + l15;
      short8v f;
      #pragma unroll
      for (int j = 0; j < 8; ++j) {
        unsigned v = q*8 + (unsigned)j;
        float a = (v < 25 && u < 25)
                ? att[(((size_t)n*3 + s)*25 + v)*25 + u] : 0.f;
        f[j] = (short)f2bf(a);
      }
      ATf[s][nt2] = f;
    }
  // wd A-frags in registers: A[m=o][k=c]
  short8v Awf[6];
  #pragma unroll
  for (int ks = 0; ks < 6; ++ks) {
    unsigned s  = (unsigned)ks >> 1;
    unsigned c0 = ((unsigned)ks & 1u)*32 + q*8;
    const float* src = wd + ((size_t)s*64 + mt*16 + l15)*64 + c0;
    short8v f;
    #pragma unroll
    for (int j = 0; j < 8; ++j) f[j] = (short)f2bf(src[j]);
    Awf[ks] = f;
  }
  __syncthreads();   // KS/KB ready

  const float* xn = x + (size_t)n * 480000;
  const float* xr = xn + (size_t)(mt*16 + l15)*7500;   // this lane's A-row
  for (unsigned t = 0; t < 30; ++t) {
    const unsigned tg = t0 + t;
    // ---- A-frag: x[c][v], k=v=q*8+j (v>=25 garbage killed by ATf zeros) ----
    const unsigned base = tg*25 + q*8;
    short8v Ax;
    #pragma unroll
    for (int j = 0; j < 8; ++j) {
      unsigned idx = base + (unsigned)j;
      if (idx > 7499u) idx = 7499u;                // stay in-bounds; value unused
      Ax[j] = (short)f2bf(xr[idx]);
    }
    // ---- P phase: P[c][u] = sum_v x[c][v]*att[v][u]; Pt[u][s*64+c] ----
    #pragma unroll
    for (int s = 0; s < 3; ++s)
      #pragma unroll
      for (int nt2 = 0; nt2 < 2; ++nt2) {
        float4v d = (float4v){0.f,0.f,0.f,0.f};
        d = MFMA_BF16(Ax, ATf[s][nt2], d);
        unsigned u  = (unsigned)nt2*16 + l15;
        unsigned kb = (unsigned)s*64 + mt*16 + q*4;
        ushort4v pk;
        #pragma unroll
        for (int r = 0; r < 4; ++r) pk[r] = f2bf(d[r]);
        *(ushort4v*)(&Pt[u*196 + kb]) = pk;
      }
    __syncthreads();
    // ---- Z phase: Z[o][u] = sum_{s,c} wd[s][o][c]*P[s*64+c][u] ----
    float4v za = (float4v){0.f,0.f,0.f,0.f}, zb = (float4v){0.f,0.f,0.f,0.f};
    #pragma unroll
    for (int ks = 0; ks < 6; ++ks) {
      short8v B0 = ld8_b64(&Pt[l15*196      + (unsigned)ks*32 + q*8]);
      short8v B1 = ld8_b64(&Pt[(16+l15)*196 + (unsigned)ks*32 + q*8]);
      za = MFMA_BF16(Awf[ks], B0, za);
      zb = MFMA_BF16(Awf[ks], B1, zb);
    }
    // ---- epilogue: BN + fp32 residual + ReLU ----
    #pragma unroll
    for (int nt2 = 0; nt2 < 2; ++nt2) {
      float4v zz = nt2 ? zb : za;
      unsigned u = (unsigned)nt2*16 + l15;
      if (u < 25) {
        #pragma unroll
        for (int r = 0; r < 4; ++r) {
          unsigned o = mt*16 + q*4 + (unsigned)r;
          float xv = xn[(size_t)o*7500 + tg*25 + u];
          float val = zz[r]*KS[o] + KB[o] + xv;
          out[((size_t)n*64 + o)*7500 + (size_t)tg*25 + u] = fmaxf(val, 0.f);
        }
      }
    }
    __syncthreads();   // Pt reads done before next t overwrites
  }
}

// ================================ launcher ==================================
extern "C" void kernel_launch(void* const* d_in, const int* in_sizes, int n_in,
                              void* d_out, int out_size, void* d_ws, size_t ws_size,
                              hipStream_t stream)
{
  (void)in_sizes; (void)n_in; (void)out_size; (void)ws_size;
  const float* x   = (const float*)d_in[0];
  const float* A   = (const float*)d_in[1];
  const float* PA  = (const float*)d_in[2];
  const float* wa  = (const float*)d_in[3];
  const float* ba  = (const float*)d_in[4];
  const float* wb  = (const float*)d_in[5];
  const float* bb  = (const float*)d_in[6];
  const float* wd  = (const float*)d_in[7];
  const float* bd  = (const float*)d_in[8];
  const float* gam = (const float*)d_in[9];
  const float* bet = (const float*)d_in[10];
  const float* mu  = (const float*)d_in[11];
  const float* var = (const float*)d_in[12];
  float* out  = (float*)d_out;
  float* part = (float*)d_ws;            // 10*64*3*625 = 1,200,000 f32 (4.8 MB)
  float* att  = part + 1200000;          // 64*3*625    =   120,000 f32

  hipLaunchKernelGGL(k1_scores, dim3(10, 64), dim3(128), 0, stream,
                     x, wa, ba, wb, bb, part);
  hipLaunchKernelGGL(k2_softmax, dim3(3, 64), dim3(256), 0, stream,
                     part, A, PA, att);
  hipLaunchKernelGGL(k3_main, dim3(10, 64), dim3(256), 0, stream,
                     x, wd, bd, gam, bet, mu, var, att, out);
}

// Round 3
// 383.600 us; speedup vs baseline: 1.8818x; 1.0172x over previous
//
#include <hip/hip_runtime.h>
#include <math.h>

// ---------------------------------------------------------------------------
// UnitGCN (AGCN block) forward.  N=64, C=OC=64, T=300, V=25, S=3, IC=16.
//   K0: zero the atomic score accumulator (ws).
//   K1: grid(25,64)x256: per (n,12-t): embed E=[wa;wb](32x64)@X via MFMA with
//       B-frags direct from global; ET round-trip in LDS; scores += Ea^T Eb
//       (MFMA over K=(t,k)); block-level results atomicAdd'd into scores.
//   K2: per (s,n): /4800, softmax over v, +A+PA -> att (fp32, ws).
//   K3: grid(30,64)x256: per (n,10-t): wd/att^T frags in registers; x A-frags
//       direct from global; P_s = Xt@att_s (MFMA); P->LDS transpose with
//       DOUBLE-BUFFERED Pt (1 barrier/t, P(t+1) overlaps Z(t));
//       Z = [wd]@Pcat (6 K-step MFMA); fused BN+fp32-residual+ReLU.
// MFMA convention (HW-verified m89/m91): D[m][n] = sum_k A_lane(m)[k]*B_lane(n)[k],
//   frag row = lane&15, k = (lane>>4)*8 + j ; C/D: col = lane&15, row = (lane>>4)*4+r.
// ---------------------------------------------------------------------------

typedef short  short4v  __attribute__((ext_vector_type(4)));
typedef short  short8v  __attribute__((ext_vector_type(8)));
typedef unsigned short ushort4v __attribute__((ext_vector_type(4)));
typedef float  float4v  __attribute__((ext_vector_type(4)));

#define MFMA_BF16(a,b,c) __builtin_amdgcn_mfma_f32_16x16x32_bf16((a),(b),(c),0,0,0)

__device__ __forceinline__ unsigned short f2bf(float f) {
  union { float f; unsigned int u; } v; v.f = f;
  unsigned int r = v.u + 0x7FFFu + ((v.u >> 16) & 1u);   // RNE
  return (unsigned short)(r >> 16);
}
// 8 bf16 from LDS via two ds_read_b64 (rows 8B-aligned)
__device__ __forceinline__ short8v ld8_b64(const unsigned short* p) {
  short4v a = *(const short4v*)p;
  short4v b = *(const short4v*)(p + 4);
  short8v r;
  r[0]=a[0]; r[1]=a[1]; r[2]=a[2]; r[3]=a[3];
  r[4]=b[0]; r[5]=b[1]; r[6]=b[2]; r[7]=b[3];
  return r;
}

// ============================ K0: zero scores ===============================
__global__ __launch_bounds__(256) void k0_zero(float* __restrict__ p, int nelem) {
  int i = blockIdx.x * 256 + threadIdx.x;
  if (i < nelem) p[i] = 0.f;
}

// ============================ K1: attention scores ==========================
// grid (25, 64) x 256 thr (4 waves). 12 t per block, 2 chunks of 6 t.
__global__ __launch_bounds__(256) void k1_scores(
    const float* __restrict__ x,  const float* __restrict__ wa,
    const float* __restrict__ ba, const float* __restrict__ wb,
    const float* __restrict__ bb, float* __restrict__ scores)
{
  __shared__ __align__(16) unsigned short ET[3][160*40]; // [s][tv][krow] bf16
  __shared__ float biasL[96];
  const unsigned tid  = threadIdx.x;
  const unsigned lane = tid & 63u, w = tid >> 6;
  const unsigned l15  = lane & 15u, q = lane >> 4;
  const unsigned n = blockIdx.y, ts = blockIdx.x;
  const unsigned t0 = ts * 12u;
  const float* xn = x + (size_t)n * 480000;

  for (unsigned i = tid; i < 96; i += 256) {
    unsigned s = i >> 5, r = i & 31u;
    biasL[i] = (r < 16) ? ba[s*16 + r] : bb[s*16 + (r-16)];
  }

  // W fragments in registers: A[m=krow][k=c], krow<16 -> wa, else wb
  short8v Wf[3][2][2];
  #pragma unroll
  for (int s = 0; s < 3; ++s)
    #pragma unroll
    for (int mt = 0; mt < 2; ++mt)
      #pragma unroll
      for (int ks = 0; ks < 2; ++ks) {
        unsigned kr = mt*16 + l15;
        unsigned c0 = ks*32 + q*8;
        const float* src = (kr < 16) ? (wa + ((size_t)s*16 + kr)*64 + c0)
                                     : (wb + ((size_t)s*16 + (kr-16))*64 + c0);
        short8v f;
        #pragma unroll
        for (int j = 0; j < 8; ++j) f[j] = (short)f2bf(src[j]);
        Wf[s][mt][ks] = f;
      }

  float4v acc[3];
  #pragma unroll
  for (int j = 0; j < 3; ++j) acc[j] = (float4v){0.f,0.f,0.f,0.f};

  __syncthreads();   // biasL ready

  for (unsigned ch = 0; ch < 2; ++ch) {            // 2 chunks of 6 t
    const unsigned tvbase = (t0 + ch*6u) * 25u;
    if (ch) __syncthreads();                       // prev chunk's reads done
    // ---- embed: tiles w, w+4, w+8 (10 tiles over 4 waves) ----
    for (unsigned nn = 0; nn < 3; ++nn) {
      unsigned nt = w + 4*nn;
      if (nt < 10) {
        unsigned tvb = nt*16 + l15;
        unsigned tvg = tvbase + tvb;
        if (tvg > 7499u) tvg = 7499u;              // clamp; values discarded
        short8v B0, B1;
        #pragma unroll
        for (int j = 0; j < 8; ++j) {
          B0[j] = (short)f2bf(xn[(size_t)(q*8 + (unsigned)j)*7500 + tvg]);
          B1[j] = (short)f2bf(xn[(size_t)(32 + q*8 + (unsigned)j)*7500 + tvg]);
        }
        #pragma unroll
        for (int s = 0; s < 3; ++s)
          #pragma unroll
          for (int mt = 0; mt < 2; ++mt) {
            float4v d = (float4v){0.f,0.f,0.f,0.f};
            d = MFMA_BF16(Wf[s][mt][0], B0, d);
            d = MFMA_BF16(Wf[s][mt][1], B1, d);
            unsigned krb = mt*16 + q*4;
            ushort4v pk;
            #pragma unroll
            for (int r = 0; r < 4; ++r) pk[r] = f2bf(d[r] + biasL[s*32 + krb + r]);
            *(ushort4v*)(&ET[s][tvb*40 + krb]) = pk;
          }
      }
    }
    __syncthreads();
    // ---- scores: D[v][u] += sum_{t,k} Ea[k][t*25+v]*Eb[k][t*25+u] ----
    #pragma unroll
    for (int j = 0; j < 3; ++j) {
      unsigned g = (unsigned)j*4 + w;              // 12 (s,mt,nt2) tasks / 4 waves
      unsigned s = g >> 2, mt = (g >> 1) & 1u, nt2 = g & 1u;
      #pragma unroll
      for (int ks = 0; ks < 3; ++ks) {
        unsigned t    = 2*ks + (q >> 1);
        unsigned kofs = 8*(q & 1u);
        short8v Af = *(const short8v*)(&ET[s][(t*25 + mt*16  + l15)*40 + kofs]);
        short8v Bf = *(const short8v*)(&ET[s][(t*25 + nt2*16 + l15)*40 + 16 + kofs]);
        acc[j] = MFMA_BF16(Af, Bf, acc[j]);
      }
    }
  }
  // ---- atomic accumulate into global scores[n][s][v][u] ----
  #pragma unroll
  for (int j = 0; j < 3; ++j) {
    unsigned g = (unsigned)j*4 + w;
    unsigned s = g >> 2, mt = (g >> 1) & 1u, nt2 = g & 1u;
    unsigned u = nt2*16 + l15;
    if (u < 25) {
      #pragma unroll
      for (int r = 0; r < 4; ++r) {
        unsigned v = mt*16 + q*4 + (unsigned)r;
        if (v < 25)
          atomicAdd(&scores[(size_t)n*1875 + s*625 + v*25 + u], acc[j][r]);
      }
    }
  }
}

// ====================== K2: softmax(v) + A + PA =============================
// grid (3, 64): one block per (s, n). 64 threads.
__global__ __launch_bounds__(64) void k2_softmax(
    const float* __restrict__ scores, const float* __restrict__ A,
    const float* __restrict__ PA, float* __restrict__ att)
{
  const unsigned tid = threadIdx.x, s = blockIdx.x, n = blockIdx.y;
  if (tid >= 25) return;
  const unsigned u = tid;
  float col[25];
  float m = -1e30f;
  #pragma unroll
  for (int v = 0; v < 25; ++v) {
    col[v] = scores[(size_t)n*1875 + s*625 + (unsigned)v*25 + u] * (1.f/4800.f);
    m = fmaxf(m, col[v]);
  }
  float S = 0.f;
  #pragma unroll
  for (int v = 0; v < 25; ++v) { col[v] = expf(col[v] - m); S += col[v]; }
  float inv = 1.f / S;
  #pragma unroll
  for (int v = 0; v < 25; ++v)
    att[(((size_t)n*3 + s)*25 + (unsigned)v)*25 + u] =
        col[v]*inv + A[s*625 + (unsigned)v*25 + u] + PA[s*625 + (unsigned)v*25 + u];
}

// ============== K3: y = x@att, z = Wd_cat@Pcat, BN+ReLU+residual ============
// grid (30, 64) x 256 thr = 4 waves; wave = c/o tile. 10 t per block.
// Double-buffered Pt: one barrier per t; P(t+1) overlaps Z(t).
__global__ __launch_bounds__(256) void k3_main(
    const float* __restrict__ x,   const float* __restrict__ wd,
    const float* __restrict__ bd,  const float* __restrict__ gam,
    const float* __restrict__ bet, const float* __restrict__ mu,
    const float* __restrict__ var, const float* __restrict__ att,
    float* __restrict__ out)
{
  __shared__ __align__(16) unsigned short Pt[2][32*196];  // [buf][u][k=s*64+c]
  __shared__ float KS[64], KB[64];
  const unsigned tid  = threadIdx.x;
  const unsigned lane = tid & 63u, mt = tid >> 6;         // wave = c/o tile
  const unsigned l15  = lane & 15u, q = lane >> 4;
  const unsigned n = blockIdx.y, t0 = blockIdx.x * 10u;

  if (tid < 64) {
    float sc = gam[tid] * rsqrtf(var[tid] + 1e-5f);
    KS[tid] = sc;
    KB[tid] = (bd[tid] + bd[64+tid] + bd[128+tid] - mu[tid]) * sc + bet[tid];
  }
  // att^T B-frags in registers: B[n=u][k=v]; zeros for v>=25 (kills x garbage)
  short8v ATf[3][2];
  #pragma unroll
  for (int s = 0; s < 3; ++s)
    #pragma unroll
    for (int nt2 = 0; nt2 < 2; ++nt2) {
      unsigned u = (unsigned)nt2*16 + l15;
      short8v f;
      #pragma unroll
      for (int j = 0; j < 8; ++j) {
        unsigned v = q*8 + (unsigned)j;
        float a = (v < 25 && u < 25)
                ? att[(((size_t)n*3 + s)*25 + v)*25 + u] : 0.f;
        f[j] = (short)f2bf(a);
      }
      ATf[s][nt2] = f;
    }
  // wd A-frags in registers: A[m=o][k=c]
  short8v Awf[6];
  #pragma unroll
  for (int ks = 0; ks < 6; ++ks) {
    unsigned s  = (unsigned)ks >> 1;
    unsigned c0 = ((unsigned)ks & 1u)*32 + q*8;
    const float* src = wd + ((size_t)s*64 + mt*16 + l15)*64 + c0;
    short8v f;
    #pragma unroll
    for (int j = 0; j < 8; ++j) f[j] = (short)f2bf(src[j]);
    Awf[ks] = f;
  }

  const float* xn = x + (size_t)n * 480000;
  const float* xr = xn + (size_t)(mt*16 + l15)*7500;   // this lane's P A-row

  // ---- prologue: P(t0) -> Pt[0] ----
  {
    const unsigned base = t0*25 + q*8;
    short8v Ax;
    #pragma unroll
    for (int j = 0; j < 8; ++j) {
      unsigned idx = base + (unsigned)j;
      if (idx > 7499u) idx = 7499u;
      Ax[j] = (short)f2bf(xr[idx]);
    }
    #pragma unroll
    for (int s = 0; s < 3; ++s)
      #pragma unroll
      for (int nt2 = 0; nt2 < 2; ++nt2) {
        float4v d = (float4v){0.f,0.f,0.f,0.f};
        d = MFMA_BF16(Ax, ATf[s][nt2], d);
        unsigned u  = (unsigned)nt2*16 + l15;
        unsigned kb = (unsigned)s*64 + mt*16 + q*4;
        ushort4v pk;
        #pragma unroll
        for (int r = 0; r < 4; ++r) pk[r] = f2bf(d[r]);
        *(ushort4v*)(&Pt[0][u*196 + kb]) = pk;
      }
  }

  for (unsigned t = 0; t < 10; ++t) {
    const unsigned cur = t & 1u, nxt = cur ^ 1u;
    const unsigned tg = t0 + t;
    __syncthreads();   // P(t) visible; Z(t-1) reads of Pt[nxt] done

    // ---- issue next A-frag loads early (overlap Z) ----
    const bool hasnext = (t + 1u < 10u);
    short8v Axn;
    if (hasnext) {
      const unsigned base = (tg + 1u)*25 + q*8;
      #pragma unroll
      for (int j = 0; j < 8; ++j) Axn[j] = (short)f2bf(xr[base + (unsigned)j]);
    }
    // ---- residual loads early ----
    float xv[2][4];
    #pragma unroll
    for (int nt2 = 0; nt2 < 2; ++nt2) {
      unsigned u = (unsigned)nt2*16 + l15;
      if (u < 25) {
        #pragma unroll
        for (int r = 0; r < 4; ++r) {
          unsigned o = mt*16 + q*4 + (unsigned)r;
          xv[nt2][r] = xn[(size_t)o*7500 + tg*25 + u];
        }
      }
    }
    // ---- Z phase: Z[o][u] = sum_{s,c} wd[s][o][c]*P[s*64+c][u] ----
    float4v za = (float4v){0.f,0.f,0.f,0.f}, zb = (float4v){0.f,0.f,0.f,0.f};
    #pragma unroll
    for (int ks = 0; ks < 6; ++ks) {
      short8v B0 = ld8_b64(&Pt[cur][l15*196      + (unsigned)ks*32 + q*8]);
      short8v B1 = ld8_b64(&Pt[cur][(16+l15)*196 + (unsigned)ks*32 + q*8]);
      za = MFMA_BF16(Awf[ks], B0, za);
      zb = MFMA_BF16(Awf[ks], B1, zb);
    }
    // ---- P(t+1) -> Pt[nxt] (no conflict with Z(t) reads of Pt[cur]) ----
    if (hasnext) {
      #pragma unroll
      for (int s = 0; s < 3; ++s)
        #pragma unroll
        for (int nt2 = 0; nt2 < 2; ++nt2) {
          float4v d = (float4v){0.f,0.f,0.f,0.f};
          d = MFMA_BF16(Axn, ATf[s][nt2], d);
          unsigned u  = (unsigned)nt2*16 + l15;
          unsigned kb = (unsigned)s*64 + mt*16 + q*4;
          ushort4v pk;
          #pragma unroll
          for (int r = 0; r < 4; ++r) pk[r] = f2bf(d[r]);
          *(ushort4v*)(&Pt[nxt][u*196 + kb]) = pk;
        }
    }
    // ---- epilogue: BN + fp32 residual + ReLU ----
    #pragma unroll
    for (int nt2 = 0; nt2 < 2; ++nt2) {
      float4v zz = nt2 ? zb : za;
      unsigned u = (unsigned)nt2*16 + l15;
      if (u < 25) {
        #pragma unroll
        for (int r = 0; r < 4; ++r) {
          unsigned o = mt*16 + q*4 + (unsigned)r;
          float val = zz[r]*KS[o] + KB[o] + xv[nt2][r];
          out[((size_t)n*64 + o)*7500 + (size_t)tg*25 + u] = fmaxf(val, 0.f);
        }
      }
    }
  }
}

// ================================ launcher ==================================
extern "C" void kernel_launch(void* const* d_in, const int* in_sizes, int n_in,
                              void* d_out, int out_size, void* d_ws, size_t ws_size,
                              hipStream_t stream)
{
  (void)in_sizes; (void)n_in; (void)out_size; (void)ws_size;
  const float* x   = (const float*)d_in[0];
  const float* A   = (const float*)d_in[1];
  const float* PA  = (const float*)d_in[2];
  const float* wa  = (const float*)d_in[3];
  const float* ba  = (const float*)d_in[4];
  const float* wb  = (const float*)d_in[5];
  const float* bb  = (const float*)d_in[6];
  const float* wd  = (const float*)d_in[7];
  const float* bd  = (const float*)d_in[8];
  const float* gam = (const float*)d_in[9];
  const float* bet = (const float*)d_in[10];
  const float* mu  = (const float*)d_in[11];
  const float* var = (const float*)d_in[12];
  float* out    = (float*)d_out;
  float* scores = (float*)d_ws;            // 64*3*625 = 120,000 f32 (480 KB)
  float* att    = scores + 120000;         // 64*3*625 = 120,000 f32

  hipLaunchKernelGGL(k0_zero, dim3((120000 + 255)/256), dim3(256), 0, stream,
                     scores, 120000);
  hipLaunchKernelGGL(k1_scores, dim3(25, 64), dim3(256), 0, stream,
                     x, wa, ba, wb, bb, scores);
  hipLaunchKernelGGL(k2_softmax, dim3(3, 64), dim3(64), 0, stream,
                     scores, A, PA, att);
  hipLaunchKernelGGL(k3_main, dim3(30, 64), dim3(256), 0, stream,
                     x, wd, bd, gam, bet, mu, var, att, out);
}

// Round 4
// 353.752 us; speedup vs baseline: 2.0406x; 1.0844x over previous
//
#include <hip/hip_runtime.h>
#include <math.h>

// ---------------------------------------------------------------------------
// UnitGCN (AGCN block) forward.  N=64, C=OC=64, T=300, V=25, S=3, IC=16.
//   K0: zero the atomic score accumulator (ws).
//   K1: grid(25,64)x256: per (n,12-t): embed E=[wa;wb](32x64)@X via MFMA with
//       B-frags direct from global; ET round-trip in LDS; scores += Ea^T Eb
//       (MFMA over K=(t,k)); block results atomicAdd'd into scores.
//   K2: per (s,n): /4800, softmax over v, +A+PA -> att (fp32, ws).
//   K3: grid(30,64)x256: per (n,10-t): wd/att^T frags + BN consts in REGISTERS;
//       x A-frags direct from global; P_s = Xt@att_s (MFMA); double-buffered
//       Pt LDS transpose (1 barrier/t); Z = [wd]@Pcat (6 K-step MFMA);
//       fused BN+fp32-residual+ReLU.
// All f32->bf16 packing via v_cvt_pk_bf16_f32 (1 VALU op / 2 elems) when the
// builtin exists; manual RNE fallback otherwise.
// MFMA convention (HW-verified m89/m91): D[m][n] = sum_k A_lane(m)[k]*B_lane(n)[k],
//   frag row = lane&15, k = (lane>>4)*8 + j ; C/D: col = lane&15, row = (lane>>4)*4+r.
// ---------------------------------------------------------------------------

typedef short  short4v  __attribute__((ext_vector_type(4)));
typedef short  short8v  __attribute__((ext_vector_type(8)));
typedef float  float4v  __attribute__((ext_vector_type(4)));

#define MFMA_BF16(a,b,c) __builtin_amdgcn_mfma_f32_16x16x32_bf16((a),(b),(c),0,0,0)

__device__ __forceinline__ unsigned short f2bf(float f) {
  union { float f; unsigned int u; } v; v.f = f;
  unsigned int r = v.u + 0x7FFFu + ((v.u >> 16) & 1u);   // RNE
  return (unsigned short)(r >> 16);
}
__device__ __forceinline__ unsigned pack2bf(float a, float b) {
#if __has_builtin(__builtin_amdgcn_cvt_pk_bf16_f32)
  typedef __bf16 bf2_t __attribute__((ext_vector_type(2)));
  bf2_t p = __builtin_amdgcn_cvt_pk_bf16_f32(a, b);
  union { bf2_t v; unsigned u; } c; c.v = p; return c.u;
#else
  return (unsigned)f2bf(a) | ((unsigned)f2bf(b) << 16);
#endif
}
__device__ __forceinline__ short8v pk8(const float* f) {
  union { unsigned u[4]; short8v s; } c;
  c.u[0] = pack2bf(f[0], f[1]); c.u[1] = pack2bf(f[2], f[3]);
  c.u[2] = pack2bf(f[4], f[5]); c.u[3] = pack2bf(f[6], f[7]);
  return c.s;
}
// 8 bf16 from LDS via two ds_read_b64 (rows 8B-aligned)
__device__ __forceinline__ short8v ld8_b64(const unsigned short* p) {
  short4v a = *(const short4v*)p;
  short4v b = *(const short4v*)(p + 4);
  short8v r;
  r[0]=a[0]; r[1]=a[1]; r[2]=a[2]; r[3]=a[3];
  r[4]=b[0]; r[5]=b[1]; r[6]=b[2]; r[7]=b[3];
  return r;
}

// ============================ K0: zero scores ===============================
__global__ __launch_bounds__(256) void k0_zero(float* __restrict__ p, int nelem) {
  int i = blockIdx.x * 256 + threadIdx.x;
  if (i < nelem) p[i] = 0.f;
}

// ============================ K1: attention scores ==========================
// grid (25, 64) x 256 thr (4 waves). 12 t per block, 2 chunks of 6 t.
__global__ __launch_bounds__(256) void k1_scores(
    const float* __restrict__ x,  const float* __restrict__ wa,
    const float* __restrict__ ba, const float* __restrict__ wb,
    const float* __restrict__ bb, float* __restrict__ scores)
{
  __shared__ __align__(16) unsigned short ET[3][160*40]; // [s][tv][krow] bf16
  const unsigned tid  = threadIdx.x;
  const unsigned lane = tid & 63u, w = tid >> 6;
  const unsigned l15  = lane & 15u, q = lane >> 4;
  const unsigned n = blockIdx.y, ts = blockIdx.x;
  const unsigned t0 = ts * 12u;
  const float* xn = x + (size_t)n * 480000;

  // W fragments in registers: A[m=krow][k=c]; mt=0 -> wa rows, mt=1 -> wb rows
  short8v Wf[3][2][2];
  #pragma unroll
  for (int s = 0; s < 3; ++s)
    #pragma unroll
    for (int mt = 0; mt < 2; ++mt)
      #pragma unroll
      for (int ks = 0; ks < 2; ++ks) {
        const float* src = (mt ? wb : wa) + ((size_t)s*16 + l15)*64
                         + (unsigned)ks*32 + q*8;
        float tf[8];
        #pragma unroll
        for (int j = 0; j < 8; ++j) tf[j] = src[j];
        Wf[s][mt][ks] = pk8(tf);
      }
  // bias in registers: output row = mt*16 + q*4 + r
  float bias[3][2][4];
  #pragma unroll
  for (int s = 0; s < 3; ++s)
    #pragma unroll
    for (int mt = 0; mt < 2; ++mt)
      #pragma unroll
      for (int r = 0; r < 4; ++r)
        bias[s][mt][r] = (mt ? bb : ba)[s*16 + q*4 + (unsigned)r];

  float4v acc[3];
  #pragma unroll
  for (int j = 0; j < 3; ++j) acc[j] = (float4v){0.f,0.f,0.f,0.f};

  for (unsigned ch = 0; ch < 2; ++ch) {            // 2 chunks of 6 t
    const unsigned tvbase = (t0 + ch*6u) * 25u;
    if (ch) __syncthreads();                       // prev chunk's reads done
    // ---- embed: tiles w, w+4, w+8 (10 tiles over 4 waves) ----
    for (unsigned nn = 0; nn < 3; ++nn) {
      unsigned nt = w + 4*nn;
      if (nt < 10) {
        unsigned tvb = nt*16 + l15;
        unsigned tvg = tvbase + tvb;
        if (tvg > 7499u) tvg = 7499u;              // clamp; values discarded
        const float* p = xn + (size_t)q*60000 + tvg;   // c = q*8 base
        float xa[8], xb[8];
        #pragma unroll
        for (int j = 0; j < 8; ++j) {
          xa[j] = p[(size_t)j*7500];
          xb[j] = p[240000 + (size_t)j*7500];
        }
        short8v B0 = pk8(xa), B1 = pk8(xb);
        #pragma unroll
        for (int s = 0; s < 3; ++s)
          #pragma unroll
          for (int mt = 0; mt < 2; ++mt) {
            float4v d = (float4v){0.f,0.f,0.f,0.f};
            d = MFMA_BF16(Wf[s][mt][0], B0, d);
            d = MFMA_BF16(Wf[s][mt][1], B1, d);
            unsigned krb = (unsigned)mt*16 + q*4;
            uint2 pk2;
            pk2.x = pack2bf(d[0] + bias[s][mt][0], d[1] + bias[s][mt][1]);
            pk2.y = pack2bf(d[2] + bias[s][mt][2], d[3] + bias[s][mt][3]);
            *(uint2*)(&ET[s][tvb*40 + krb]) = pk2;
          }
      }
    }
    __syncthreads();
    // ---- scores: D[v][u] += sum_{t,k} Ea[k][t*25+v]*Eb[k][t*25+u] ----
    #pragma unroll
    for (int j = 0; j < 3; ++j) {
      unsigned g = (unsigned)j*4 + w;              // 12 (s,mt,nt2) tasks / 4 waves
      unsigned s = g >> 2, mt = (g >> 1) & 1u, nt2 = g & 1u;
      #pragma unroll
      for (int ks = 0; ks < 3; ++ks) {
        unsigned t    = 2*ks + (q >> 1);
        unsigned kofs = 8*(q & 1u);
        short8v Af = *(const short8v*)(&ET[s][(t*25 + mt*16  + l15)*40 + kofs]);
        short8v Bf = *(const short8v*)(&ET[s][(t*25 + nt2*16 + l15)*40 + 16 + kofs]);
        acc[j] = MFMA_BF16(Af, Bf, acc[j]);
      }
    }
  }
  // ---- atomic accumulate into global scores[n][s][v][u] ----
  #pragma unroll
  for (int j = 0; j < 3; ++j) {
    unsigned g = (unsigned)j*4 + w;
    unsigned s = g >> 2, mt = (g >> 1) & 1u, nt2 = g & 1u;
    unsigned u = nt2*16 + l15;
    if (u < 25) {
      #pragma unroll
      for (int r = 0; r < 4; ++r) {
        unsigned v = mt*16 + q*4 + (unsigned)r;
        if (v < 25)
          atomicAdd(&scores[(size_t)n*1875 + s*625 + v*25 + u], acc[j][r]);
      }
    }
  }
}

// ====================== K2: softmax(v) + A + PA =============================
// grid (3, 64): one block per (s, n). 64 threads.
__global__ __launch_bounds__(64) void k2_softmax(
    const float* __restrict__ scores, const float* __restrict__ A,
    const float* __restrict__ PA, float* __restrict__ att)
{
  const unsigned tid = threadIdx.x, s = blockIdx.x, n = blockIdx.y;
  if (tid >= 25) return;
  const unsigned u = tid;
  float col[25];
  float m = -1e30f;
  #pragma unroll
  for (int v = 0; v < 25; ++v) {
    col[v] = scores[(size_t)n*1875 + s*625 + (unsigned)v*25 + u] * (1.f/4800.f);
    m = fmaxf(m, col[v]);
  }
  float S = 0.f;
  #pragma unroll
  for (int v = 0; v < 25; ++v) { col[v] = expf(col[v] - m); S += col[v]; }
  float inv = 1.f / S;
  #pragma unroll
  for (int v = 0; v < 25; ++v)
    att[(((size_t)n*3 + s)*25 + (unsigned)v)*25 + u] =
        col[v]*inv + A[s*625 + (unsigned)v*25 + u] + PA[s*625 + (unsigned)v*25 + u];
}

// ============== K3: y = x@att, z = Wd_cat@Pcat, BN+ReLU+residual ============
// grid (30, 64) x 256 thr = 4 waves; wave = c/o tile. 10 t per block.
// Double-buffered Pt: one barrier per t; P(t+1) overlaps Z(t).
__global__ __launch_bounds__(256) void k3_main(
    const float* __restrict__ x,   const float* __restrict__ wd,
    const float* __restrict__ bd,  const float* __restrict__ gam,
    const float* __restrict__ bet, const float* __restrict__ mu,
    const float* __restrict__ var, const float* __restrict__ att,
    float* __restrict__ out)
{
  __shared__ __align__(16) unsigned short Pt[2][32*196];  // [buf][u][k=s*64+c]
  const unsigned tid  = threadIdx.x;
  const unsigned lane = tid & 63u, mt = tid >> 6;         // wave = c/o tile
  const unsigned l15  = lane & 15u, q = lane >> 4;
  const unsigned n = blockIdx.y, t0 = blockIdx.x * 10u;

  // BN consts in registers for this lane's 4 output rows o = mt*16+q*4+r
  float ksr[4], kbr[4];
  #pragma unroll
  for (int r = 0; r < 4; ++r) {
    unsigned o = mt*16 + q*4 + (unsigned)r;
    float sc = gam[o] * rsqrtf(var[o] + 1e-5f);
    ksr[r] = sc;
    kbr[r] = (bd[o] + bd[64+o] + bd[128+o] - mu[o]) * sc + bet[o];
  }
  // att^T B-frags in registers: B[n=u][k=v]; zeros for v>=25 (kills x garbage)
  short8v ATf[3][2];
  #pragma unroll
  for (int s = 0; s < 3; ++s)
    #pragma unroll
    for (int nt2 = 0; nt2 < 2; ++nt2) {
      unsigned u = (unsigned)nt2*16 + l15;
      float tf[8];
      #pragma unroll
      for (int j = 0; j < 8; ++j) {
        unsigned v = q*8 + (unsigned)j;
        tf[j] = (v < 25 && u < 25) ? att[(((size_t)n*3 + s)*25 + v)*25 + u] : 0.f;
      }
      ATf[s][nt2] = pk8(tf);
    }
  // wd A-frags in registers: A[m=o][k=c]
  short8v Awf[6];
  #pragma unroll
  for (int ks = 0; ks < 6; ++ks) {
    const float* src = wd + ((size_t)((unsigned)ks>>1)*64 + mt*16 + l15)*64
                     + ((unsigned)ks & 1u)*32 + q*8;
    float tf[8];
    #pragma unroll
    for (int j = 0; j < 8; ++j) tf[j] = src[j];
    Awf[ks] = pk8(tf);
  }
  // shared residual/output offsets: o*7500 + u  (fits u32)
  unsigned offs[2][4];
  const bool valid1 = (l15 < 9);                    // u=16+l15 < 25
  #pragma unroll
  for (int nt2 = 0; nt2 < 2; ++nt2)
    #pragma unroll
    for (int r = 0; r < 4; ++r)
      offs[nt2][r] = (mt*16 + q*4 + (unsigned)r)*7500u + (unsigned)nt2*16 + l15;

  const float* xn = x + (size_t)n * 480000;
  float*       on = (float*)out + (size_t)n * 480000;
  const float* xr = xn + (size_t)(mt*16 + l15)*7500;   // this lane's P A-row

  // ---- prologue: P(t0) -> Pt[0] ----
  {
    const float* pa = xr + t0*25 + q*8;              // max idx 7313 < 7500
    float fa[8];
    #pragma unroll
    for (int j = 0; j < 8; ++j) fa[j] = pa[j];
    short8v Ax = pk8(fa);
    #pragma unroll
    for (int s = 0; s < 3; ++s)
      #pragma unroll
      for (int nt2 = 0; nt2 < 2; ++nt2) {
        float4v d = (float4v){0.f,0.f,0.f,0.f};
        d = MFMA_BF16(Ax, ATf[s][nt2], d);
        unsigned u  = (unsigned)nt2*16 + l15;
        unsigned kb = (unsigned)s*64 + mt*16 + q*4;
        uint2 pk2; pk2.x = pack2bf(d[0], d[1]); pk2.y = pack2bf(d[2], d[3]);
        *(uint2*)(&Pt[0][u*196 + kb]) = pk2;
      }
  }

  for (unsigned t = 0; t < 10; ++t) {
    const unsigned cur = t & 1u, nxt = cur ^ 1u;
    const unsigned tg = t0 + t, t25 = tg*25;
    __syncthreads();   // P(t) visible; Z(t-1) reads of Pt[nxt] done

    // ---- next A-frag loads early (overlap Z) ----
    const bool hasnext = (t + 1u < 10u);
    short8v Axn;
    if (hasnext) {
      const float* pa = xr + t25 + 25 + q*8;
      float fa[8];
      #pragma unroll
      for (int j = 0; j < 8; ++j) fa[j] = pa[j];
      Axn = pk8(fa);
    }
    // ---- residual loads early ----
    float xv[2][4];
    #pragma unroll
    for (int nt2 = 0; nt2 < 2; ++nt2)
      if (nt2 == 0 || valid1) {
        #pragma unroll
        for (int r = 0; r < 4; ++r) xv[nt2][r] = xn[offs[nt2][r] + t25];
      }
    // ---- Z phase: Z[o][u] = sum_{s,c} wd[s][o][c]*P[s*64+c][u] ----
    float4v za = (float4v){0.f,0.f,0.f,0.f}, zb = (float4v){0.f,0.f,0.f,0.f};
    #pragma unroll
    for (int ks = 0; ks < 6; ++ks) {
      short8v B0 = ld8_b64(&Pt[cur][l15*196      + (unsigned)ks*32 + q*8]);
      short8v B1 = ld8_b64(&Pt[cur][(16+l15)*196 + (unsigned)ks*32 + q*8]);
      za = MFMA_BF16(Awf[ks], B0, za);
      zb = MFMA_BF16(Awf[ks], B1, zb);
    }
    // ---- P(t+1) -> Pt[nxt] ----
    if (hasnext) {
      #pragma unroll
      for (int s = 0; s < 3; ++s)
        #pragma unroll
        for (int nt2 = 0; nt2 < 2; ++nt2) {
          float4v d = (float4v){0.f,0.f,0.f,0.f};
          d = MFMA_BF16(Axn, ATf[s][nt2], d);
          unsigned u  = (unsigned)nt2*16 + l15;
          unsigned kb = (unsigned)s*64 + mt*16 + q*4;
          uint2 pk2; pk2.x = pack2bf(d[0], d[1]); pk2.y = pack2bf(d[2], d[3]);
          *(uint2*)(&Pt[nxt][u*196 + kb]) = pk2;
        }
    }
    // ---- epilogue: BN + fp32 residual + ReLU ----
    #pragma unroll
    for (int nt2 = 0; nt2 < 2; ++nt2) {
      float4v zz = nt2 ? zb : za;
      if (nt2 == 0 || valid1) {
        #pragma unroll
        for (int r = 0; r < 4; ++r) {
          float val = zz[r]*ksr[r] + kbr[r] + xv[nt2][r];
          on[offs[nt2][r] + t25] = fmaxf(val, 0.f);
        }
      }
    }
  }
}

// ================================ launcher ==================================
extern "C" void kernel_launch(void* const* d_in, const int* in_sizes, int n_in,
                              void* d_out, int out_size, void* d_ws, size_t ws_size,
                              hipStream_t stream)
{
  (void)in_sizes; (void)n_in; (void)out_size; (void)ws_size;
  const float* x   = (const float*)d_in[0];
  const float* A   = (const float*)d_in[1];
  const float* PA  = (const float*)d_in[2];
  const float* wa  = (const float*)d_in[3];
  const float* ba  = (const float*)d_in[4];
  const float* wb  = (const float*)d_in[5];
  const float* bb  = (const float*)d_in[6];
  const float* wd  = (const float*)d_in[7];
  const float* bd  = (const float*)d_in[8];
  const float* gam = (const float*)d_in[9];
  const float* bet = (const float*)d_in[10];
  const float* mu  = (const float*)d_in[11];
  const float* var = (const float*)d_in[12];
  float* out    = (float*)d_out;
  float* scores = (float*)d_ws;            // 64*3*625 = 120,000 f32 (480 KB)
  float* att    = scores + 120000;         // 64*3*625 = 120,000 f32

  hipLaunchKernelGGL(k0_zero, dim3((120000 + 255)/256), dim3(256), 0, stream,
                     scores, 120000);
  hipLaunchKernelGGL(k1_scores, dim3(25, 64), dim3(256), 0, stream,
                     x, wa, ba, wb, bb, scores);
  hipLaunchKernelGGL(k2_softmax, dim3(3, 64), dim3(64), 0, stream,
                     scores, A, PA, att);
  hipLaunchKernelGGL(k3_main, dim3(30, 64), dim3(256), 0, stream,
                     x, wd, bd, gam, bet, mu, var, att, out);
}